// Round 9
// baseline (149.936 us; speedup 1.0000x reference)
//
#include <hip/hip_runtime.h>
#include <hip/hip_bf16.h>

// Shapes: x(8,16,4,64,64) f32, W(256,16,5,5) f32, b(1,1,8,32) f32
// out(8,32,8,64,64) f32.
//
// Verified reinterpretations (R1/R3/R4/R6/R7/R8 passing):
//   conv input  t2[n,a,h,w] = x[b0, w&15, ci, a*4+(h>>4), (h&15)*4+(w>>4)],
//     n = ci*8 + b0  (algebraic expansion of the reference's reshape chain;
//     one float4 x[b0,a1,ci,a*4+(h>>4),(h&15)*4 .. +3] = t2[n,a,h,a1+16q])
//   votes flat (n,oc,y,x) reinterpreted by routing as (bv,civ,h,w,o,ao),
//     n = bv*4 + civ.
// Conv = implicit GEMM on v_mfma_f32_16x16x32_f16 (layouts m89/m120),
// operand order mfma(A=pixels, B=weights) so D rows = x -> 8B stores (R8 win).
// R5: no conv+routing fusion (w-sparse out -> 16x write amp).
// R6: 2-row conv tile -> VGPR/occupancy collapse. R9: conv gathers x directly
// (kills pack kernel + halo memset + th round-trip).

typedef _Float16 half8 __attribute__((ext_vector_type(8)));
typedef _Float16 half4v __attribute__((ext_vector_type(4)));
typedef float floatx4 __attribute__((ext_vector_type(4)));

#define EPSF 1e-7f

// W (oc,a,ky,kx) f32 -> Wp (kk=0..25, oc, a) f16; plane kk==25 is zeros.
__global__ __launch_bounds__(256) void k_packw(const float* __restrict__ W,
                                               _Float16* __restrict__ Wp) {
  int id = blockIdx.x * 256 + threadIdx.x;      // 106,496 = 26*4096
  int a  = id & 15;
  int oc = (id >> 4) & 255;
  int kk = id >> 12;
  Wp[id] = (kk < 25) ? (_Float16)W[oc * 400 + a * 25 + kk] : (_Float16)0.0f;
}

// Conv: block (y, n); 4 waves; wave wv: M = 64 x-pixels, N = oc [wv*64,+64),
// 4x4 tiles of mfma(pixels, weights). Slab gathered from x directly.
__global__ __launch_bounds__(256) void k_conv(
    const float* __restrict__ x, const _Float16* __restrict__ Wp,
    _Float16* __restrict__ votes) {
  __shared__ _Float16 slab[5440];     // [ah=2][rr=5][cc=68][8a]  10.6 KB
  const int y = blockIdx.x;           // 0..63
  const int n = blockIdx.y;           // 0..31
  const int tid = threadIdx.x;
  const int ci = n >> 3, b0 = n & 7;
  const float* xb = x + b0 * 262144 + ci * 4096;

  // Gather staging: c = (a*5 + rr)*16 + a1, 1280 float4 loads.
  for (int c = tid; c < 1280; c += 256) {
    int a   = c / 80;
    int rem = c - a * 80;
    int rr  = rem >> 4;
    int a1  = rem & 15;
    int h   = y + rr - 2;
    int ah  = a >> 3, sub = a & 7;
    _Float16* sb = slab + ((ah * 5 + rr) * 68 + a1 + 2) * 8 + sub;
    if (h >= 0 && h < 64) {
      float4 v = *(const float4*)(xb + a1 * 16384
                                  + (a * 4 + (h >> 4)) * 64 + (h & 15) * 4);
      sb[0 * 128]  = (_Float16)v.x;   // cc = a1+2 + 16q, stride 16*8 halves
      sb[16 * 8]   = (_Float16)v.y;
      sb[32 * 8]   = (_Float16)v.z;
      sb[48 * 8]   = (_Float16)v.w;
    } else {
      sb[0 * 128]  = (_Float16)0.0f;
      sb[16 * 8]   = (_Float16)0.0f;
      sb[32 * 8]   = (_Float16)0.0f;
      sb[48 * 8]   = (_Float16)0.0f;
    }
  }
  // Halo columns {0,1,66,67}: 2ah x 5rr x 4cols half8 chunks = 40.
  if (tid < 40) {
    int ah  = tid / 20;
    int rem = tid - ah * 20;
    int rr  = rem >> 2;
    int hci = rem & 3;
    int hc  = (hci < 2) ? hci : (64 + hci);     // 0,1,66,67
    half8 z = {};
    *(half8*)(slab + ((ah * 5 + rr) * 68 + hc) * 8) = z;
  }
  __syncthreads();

  const int lane  = tid & 63;
  const int wv    = tid >> 6;
  const int col16 = lane & 15;
  const int quad  = lane >> 4;      // 0..3
  const int t     = quad >> 1;      // tap-within-pair
  const int a0h   = quad & 1;       // atom-half
  const int m0    = wv * 64;        // oc base

  floatx4 acc[4][4] = {};           // [xt][oct]

  // Weight B-frag base: plane(2s+t) -> wb + s*8192; plane 25 is zeros.
  const _Float16* wb = Wp + (size_t)t * 4096 + (m0 + col16) * 16 + a0h * 8;
  half8 wf[4], wf1[4], wf2[4], pf[4], pf1[4];
#pragma unroll
  for (int oct = 0; oct < 4; ++oct) {
    wf[oct]  = *(const half8*)(wb + oct * 256);
    wf1[oct] = *(const half8*)(wb + 8192 + oct * 256);
  }

  // Pixel A-frags for s=0: tap kkb = t (ky=0, kx=t).
#pragma unroll
  for (int xt = 0; xt < 4; ++xt)
    pf[xt] = *(const half8*)(slab + (a0h * 340 + xt * 16 + col16 + t) * 8);

  for (int s = 0; s < 13; ++s) {
    int s2 = (s + 2 < 13) ? s + 2 : 12;
#pragma unroll
    for (int oct = 0; oct < 4; ++oct)
      wf2[oct] = *(const half8*)(wb + (size_t)s2 * 8192 + oct * 256);
    int kkb1 = 2 * (s + 1) + t; if (kkb1 > 24) kkb1 = 24;  // pixel addr clamp
    int ky1 = kkb1 / 5, kx1 = kkb1 - ky1 * 5;
    const _Float16* lb1 = slab + (a0h * 340 + ky1 * 68 + col16 + kx1) * 8;
#pragma unroll
    for (int xt = 0; xt < 4; ++xt)
      pf1[xt] = *(const half8*)(lb1 + xt * 128);
#pragma unroll
    for (int xt = 0; xt < 4; ++xt)
#pragma unroll
      for (int oct = 0; oct < 4; ++oct)
        acc[xt][oct] = __builtin_amdgcn_mfma_f32_16x16x32_f16(
            pf[xt], wf[oct], acc[xt][oct], 0, 0, 0);
#pragma unroll
    for (int oct = 0; oct < 4; ++oct) { wf[oct] = wf1[oct]; wf1[oct] = wf2[oct]; }
#pragma unroll
    for (int xt = 0; xt < 4; ++xt) pf[xt] = pf1[xt];
  }

  // D[row = x = xt*16 + quad*4 + r][col = oc = oct*16 + col16]
  // -> votes[n, oc, y, x]: 4 consecutive x per lane = one 8B store.
  _Float16* vbase = votes + (size_t)n * 1048576 + y * 64;
#pragma unroll
  for (int oct = 0; oct < 4; ++oct) {
    int oc = m0 + oct * 16 + col16;
#pragma unroll
    for (int xt = 0; xt < 4; ++xt) {
      half4v o4;
      o4.x = (_Float16)acc[xt][oct][0];
      o4.y = (_Float16)acc[xt][oct][1];
      o4.z = (_Float16)acc[xt][oct][2];
      o4.w = (_Float16)acc[xt][oct][3];
      *(half4v*)(vbase + (size_t)oc * 4096 + xt * 16 + quad * 4) = o4;
    }
  }
}

// Routing v4 (R8-proven): block = (bv, h, 16 w); 4 waves x 4 positions.
// Iter-0 softmax = exact 1/8; iters 1-2 max-free softmax (|logit| small).
__global__ __launch_bounds__(256) void k_routing4(
    const _Float16* __restrict__ votes, const float* __restrict__ bias,
    float* __restrict__ out) {
  __shared__ float so[256 * 17];        // 17.0 KB
  const int tid  = threadIdx.x;
  const int lane = tid & 63;
  const int wv   = tid >> 6;
  const int bid  = blockIdx.x;          // 2048
  const int bv = bid >> 8;
  const int h  = (bid >> 2) & 63;
  const int W0 = (bid & 3) * 16;

  float4 bia = *(const float4*)(bias + lane * 4);
  const int o = lane >> 3;
  const int m = lane & 7;

  float act[4][4];

  const _Float16* vb0 = votes + (size_t)bv * 4194304 + h * 16384
                        + (W0 + wv * 4) * 256 + lane * 4;

#pragma unroll
  for (int k = 0; k < 4; ++k) {
    float4 v[4];
#pragma unroll
    for (int i = 0; i < 4; ++i) {
      half4v hv = *(const half4v*)(vb0 + k * 256 + (size_t)i * 1048576);
      v[i] = make_float4((float)hv.x, (float)hv.y, (float)hv.z, (float)hv.w);
    }

    // ---- r = 0: route = 1/8 exactly ----
    float pr[4] = {bia.x, bia.y, bia.z, bia.w};
#pragma unroll
    for (int i = 0; i < 4; ++i) {
      pr[0] = fmaf(0.125f, v[i].x, pr[0]);
      pr[1] = fmaf(0.125f, v[i].y, pr[1]);
      pr[2] = fmaf(0.125f, v[i].z, pr[2]);
      pr[3] = fmaf(0.125f, v[i].w, pr[3]);
    }
    float sq = pr[0]*pr[0] + pr[1]*pr[1] + pr[2]*pr[2] + pr[3]*pr[3];
    sq += __shfl_xor(sq, 1, 64);
    sq += __shfl_xor(sq, 2, 64);
    sq += __shfl_xor(sq, 4, 64);
    float scale = sq / (1.f + sq) / sqrtf(sq + EPSF);
    float a0 = pr[0]*scale, a1 = pr[1]*scale, a2 = pr[2]*scale, a3 = pr[3]*scale;

    float logit[4];
#pragma unroll
    for (int i = 0; i < 4; ++i) {
      float ag = v[i].x*a0 + v[i].y*a1 + v[i].z*a2 + v[i].w*a3;
      ag += __shfl_xor(ag, 1, 64);
      ag += __shfl_xor(ag, 2, 64);
      ag += __shfl_xor(ag, 4, 64);
      logit[i] = ag;
    }

    // ---- r = 1, 2 ----
#pragma unroll
    for (int r = 1; r < 3; ++r) {
      float route[4];
#pragma unroll
      for (int i = 0; i < 4; ++i) {
        float e = __expf(logit[i]);
        float s = e;
        s += __shfl_xor(s, 8, 64);
        s += __shfl_xor(s, 16, 64);
        s += __shfl_xor(s, 32, 64);
        route[i] = e / s;
      }
      pr[0] = bia.x; pr[1] = bia.y; pr[2] = bia.z; pr[3] = bia.w;
#pragma unroll
      for (int i = 0; i < 4; ++i) {
        pr[0] = fmaf(route[i], v[i].x, pr[0]);
        pr[1] = fmaf(route[i], v[i].y, pr[1]);
        pr[2] = fmaf(route[i], v[i].z, pr[2]);
        pr[3] = fmaf(route[i], v[i].w, pr[3]);
      }
      sq = pr[0]*pr[0] + pr[1]*pr[1] + pr[2]*pr[2] + pr[3]*pr[3];
      sq += __shfl_xor(sq, 1, 64);
      sq += __shfl_xor(sq, 2, 64);
      sq += __shfl_xor(sq, 4, 64);
      scale = sq / (1.f + sq) / sqrtf(sq + EPSF);
      a0 = pr[0]*scale; a1 = pr[1]*scale; a2 = pr[2]*scale; a3 = pr[3]*scale;

      if (r == 1) {
#pragma unroll
        for (int i = 0; i < 4; ++i) {
          float ag = v[i].x*a0 + v[i].y*a1 + v[i].z*a2 + v[i].w*a3;
          ag += __shfl_xor(ag, 1, 64);
          ag += __shfl_xor(ag, 2, 64);
          ag += __shfl_xor(ag, 4, 64);
          logit[i] += ag;
        }
      }
    }
    act[k][0] = a0; act[k][1] = a1; act[k][2] = a2; act[k][3] = a3;
  }

  // Stage to LDS, then coalesced writeout: 256 (a,o) rows x 16 w floats.
#pragma unroll
  for (int k = 0; k < 4; ++k)
#pragma unroll
    for (int j = 0; j < 4; ++j)
      so[((m * 4 + j) * 8 + o) * 17 + wv * 4 + k] = act[k][j];
  __syncthreads();

  float* ob = out + (size_t)bv * 1048576 + h * 64 + W0;
  for (int p = 0; p < 4; ++p) {
    int rg = p * 64 + (tid >> 2);       // 0..255 = a*8+o
    int w0 = (tid & 3) * 4;
    const float* sp = so + rg * 17 + w0;
    float4 val = make_float4(sp[0], sp[1], sp[2], sp[3]);
    *(float4*)(ob + (size_t)rg * 4096 + w0) = val;
  }
}

extern "C" void kernel_launch(void* const* d_in, const int* in_sizes, int n_in,
                              void* d_out, int out_size, void* d_ws, size_t ws_size,
                              hipStream_t stream) {
  const float* x  = (const float*)d_in[0];
  const float* W  = (const float*)d_in[1];
  const float* b  = (const float*)d_in[2];
  float* out = (float*)d_out;

  _Float16* Wp    = (_Float16*)d_ws;            // 106,496 halves (208 KB)
  _Float16* votes = Wp + 106496;                // 33,554,432 halves (64 MB)

  k_packw<<<416, 256, 0, stream>>>(W, Wp);
  k_conv<<<dim3(64, 32), 256, 0, stream>>>(x, Wp, votes);
  k_routing4<<<2048, 256, 0, stream>>>(votes, b, out);
}